// Round 7
// baseline (171.737 us; speedup 1.0000x reference)
//
#include <hip/hip_runtime.h>

// DomDepResidualLayer: out = relu(h0 + (mixed @ we1^T + b1))
//   enc   = h0 @ we0^T + b0                         [16384,128]
//   acts  = relu(einsum('nd,mkd->mnk', enc, wm)+bm) (never materialized)
//   gate  = softmax(enc @ ws^T + bs, axis=0)        [16384,128]
//   mixed[n,i] = sum_j acts[i,n,j]*gate[n,j]        [16384,128]
// v8: k_mix 2x-unrolled ping-pong (GA/GB), b[s] reloads interleaved inside the
// MFMA block, G(next) issued right after MFMAs -> all loads have >=650cy
// issue-to-use distance with zero register-array rotation. softmax @1024 thr.

#define N_TOK   16384
#define EMB     1024
#define MDIM    128

typedef __attribute__((ext_vector_type(8))) short   short8;   // 8 bf16 = 1 MFMA frag
typedef __attribute__((ext_vector_type(4))) float   f32x4;
typedef __attribute__((ext_vector_type(4))) float   fv4;
typedef __attribute__((ext_vector_type(4))) unsigned short us4;

static __device__ __forceinline__ unsigned short f2bf(float f) {
    union { float f; unsigned u; } v; v.f = f;
    unsigned r = v.u + 0x7FFFu + ((v.u >> 16) & 1u);   // RNE
    return (unsigned short)(r >> 16);
}
static __device__ __forceinline__ float bf2f_lo(unsigned u) {
    union { unsigned u; float f; } v; v.u = u << 16; return v.f;
}
static __device__ __forceinline__ float bf2f_hi(unsigned u) {
    union { unsigned u; float f; } v; v.u = u & 0xffff0000u; return v.f;
}

// ---------------- fused fp32 -> bf16 conversion of all weights ----------------
__global__ void k_convert_all(const float* __restrict__ wm_w,
                              const float* __restrict__ we0_w,
                              const float* __restrict__ we1_w,
                              const float* __restrict__ ws_w,
                              unsigned short* __restrict__ dst) {
    const int NFV4 = 593920;
    for (int i = blockIdx.x * blockDim.x + threadIdx.x; i < NFV4;
         i += gridDim.x * blockDim.x) {
        const float* src;
        if (i < 524288)       src = wm_w  + (size_t)i * 4;
        else if (i < 557056)  src = we0_w + (size_t)(i - 524288) * 4;
        else if (i < 589824)  src = we1_w + (size_t)(i - 557056) * 4;
        else                  src = ws_w  + (size_t)(i - 589824) * 4;
        fv4 v = *(const fv4*)src;
        us4 o;
        o.x = f2bf(v.x); o.y = f2bf(v.y); o.z = f2bf(v.z); o.w = f2bf(v.w);
        *(us4*)(dst + (size_t)i * 4) = o;
    }
}

// Fragment-tiled bf16 layout for a [N,128] matrix X (2048 bf16 per 16-tok tile):
//   offset(tok,d) = (tok>>4)*2048 + (d>>5)*512 + (((d&31)>>3)*16 + (tok&15))*8 + (d&7)

// ---------------- enc = h0 @ we0^T + b0, fused logits^T = enc @ ws^T + bs ----------------
__global__ __launch_bounds__(256) void k_enc(const float* __restrict__ h0,
                                             const unsigned short* __restrict__ we0b,
                                             const unsigned short* __restrict__ wsb,
                                             const float* __restrict__ we0_bias,
                                             const float* __restrict__ ws_bias,
                                             unsigned short* __restrict__ encT,
                                             float* __restrict__ logT) {
    __shared__ unsigned short Wt[128 * 128];
    __shared__ unsigned short Ht[32 * 128];
    __shared__ unsigned short Et[32 * 128];

    const int tid = threadIdx.x;
    const int lane = tid & 63, w = tid >> 6;
    const int c = lane & 15, g = lane >> 4;
    const int wd = w >> 1, wt = w & 1;
    const int t0 = blockIdx.x * 32;

    f32x4 acc[4] = {};
    for (int ks = 0; ks < 8; ++ks) {
        #pragma unroll
        for (int it = 0; it < 8; ++it) {
            int m = it * 256 + tid;
            int row = m >> 4, gc = m & 15;
            short8 v = *(const short8*)(we0b + row * 1024 + ks * 128 + gc * 8);
            *(short8*)&Wt[row * 128 + ((gc ^ (row & 7)) * 8)] = v;
        }
        #pragma unroll
        for (int it = 0; it < 2; ++it) {
            int m = it * 256 + tid;
            int row = m >> 4, gc = m & 15;
            const float* hp = h0 + (size_t)(t0 + row) * 1024 + ks * 128 + gc * 8;
            fv4 v0 = *(const fv4*)hp;
            fv4 v1 = *(const fv4*)(hp + 4);
            short8 ov;
            ov[0] = (short)f2bf(v0.x); ov[1] = (short)f2bf(v0.y);
            ov[2] = (short)f2bf(v0.z); ov[3] = (short)f2bf(v0.w);
            ov[4] = (short)f2bf(v1.x); ov[5] = (short)f2bf(v1.y);
            ov[6] = (short)f2bf(v1.z); ov[7] = (short)f2bf(v1.w);
            *(short8*)&Ht[row * 128 + ((gc ^ (row & 7)) * 8)] = ov;
        }
        __syncthreads();
        #pragma unroll
        for (int s = 0; s < 4; ++s) {
            int gk = s * 4 + g;
            int brow = wt * 16 + c;
            short8 b = *(const short8*)&Ht[brow * 128 + ((gk ^ (brow & 7)) * 8)];
            #pragma unroll
            for (int jf = 0; jf < 4; ++jf) {
                int j = wd * 64 + jf * 16 + c;
                short8 a = *(const short8*)&Wt[j * 128 + ((gk ^ (j & 7)) * 8)];
                acc[jf] = __builtin_amdgcn_mfma_f32_16x16x32_bf16(a, b, acc[jf], 0, 0, 0);
            }
        }
        __syncthreads();
    }
    const int tile = blockIdx.x * 2 + wt;
    const int erow = wt * 16 + c;
    #pragma unroll
    for (int f = 0; f < 4; ++f) {
        int d0 = wd * 64 + f * 16 + 4 * g;
        int s = wd * 2 + (f >> 1);
        int chunk = ((f & 1) ? 2 : 0) + (g >> 1);
        int e = (g & 1) * 4;
        fv4 bi = *(const fv4*)(we0_bias + d0);
        us4 o;
        o.x = f2bf(acc[f][0] + bi.x);
        o.y = f2bf(acc[f][1] + bi.y);
        o.z = f2bf(acc[f][2] + bi.z);
        o.w = f2bf(acc[f][3] + bi.w);
        *(us4*)(encT + (size_t)tile * 2048 + s * 512 + (chunk * 16 + c) * 8 + e) = o;
        int cg = d0 >> 3, off = d0 & 7;
        *(us4*)&Et[erow * 128 + ((cg ^ (erow & 7)) * 8) + off] = o;
    }
    __syncthreads();

    short8 al[4][4];
    #pragma unroll
    for (int jf = 0; jf < 4; ++jf)
        #pragma unroll
        for (int s = 0; s < 4; ++s)
            al[jf][s] = *(const short8*)(wsb + (wd * 64 + jf * 16 + c) * 128 + s * 32 + g * 8);
    short8 bl[4];
    #pragma unroll
    for (int s = 0; s < 4; ++s) {
        int cg2 = s * 4 + g;
        bl[s] = *(const short8*)&Et[erow * 128 + ((cg2 ^ (erow & 7)) * 8)];
    }
    f32x4 acc2[4] = {};
    #pragma unroll
    for (int s = 0; s < 4; ++s)
        #pragma unroll
        for (int jf = 0; jf < 4; ++jf)
            acc2[jf] = __builtin_amdgcn_mfma_f32_16x16x32_bf16(al[jf][s], bl[s], acc2[jf], 0, 0, 0);
    const int tokc = t0 + wt * 16 + c;
    #pragma unroll
    for (int jf = 0; jf < 4; ++jf) {
        int m0 = wd * 64 + jf * 16 + 4 * g;
        fv4 bs = *(const fv4*)(ws_bias + m0);
        logT[(size_t)(m0 + 0) * N_TOK + tokc] = acc2[jf][0] + bs.x;
        logT[(size_t)(m0 + 1) * N_TOK + tokc] = acc2[jf][1] + bs.y;
        logT[(size_t)(m0 + 2) * N_TOK + tokc] = acc2[jf][2] + bs.z;
        logT[(size_t)(m0 + 3) * N_TOK + tokc] = acc2[jf][3] + bs.w;
    }
}

// ---------------- gate = softmax over axis 0, per column m ----------------
// 1024 threads/block, one block per column m.
__global__ __launch_bounds__(1024) void k_softmax0(const float* __restrict__ logT,
                                                   unsigned short* __restrict__ gateT) {
    __shared__ float red[32];
    const int m = blockIdx.x;
    const int tid = threadIdx.x;
    const int lane = tid & 63, wv = tid >> 6;   // 16 waves
    const float* row = logT + (size_t)m * N_TOK;

    fv4 v[4];
    float vmax = -3.0e38f;
    #pragma unroll
    for (int it = 0; it < 4; ++it) {
        v[it] = *(const fv4*)(row + it * 4096 + tid * 4);
        vmax = fmaxf(vmax, fmaxf(fmaxf(v[it].x, v[it].y), fmaxf(v[it].z, v[it].w)));
    }
    #pragma unroll
    for (int o = 32; o > 0; o >>= 1) vmax = fmaxf(vmax, __shfl_xor(vmax, o));
    if (lane == 0) red[wv] = vmax;
    __syncthreads();
    float bmax = -3.0e38f;
    #pragma unroll
    for (int k = 0; k < 16; ++k) bmax = fmaxf(bmax, red[k]);

    float s = 0.f;
    #pragma unroll
    for (int it = 0; it < 4; ++it) {
        v[it].x = __expf(v[it].x - bmax); v[it].y = __expf(v[it].y - bmax);
        v[it].z = __expf(v[it].z - bmax); v[it].w = __expf(v[it].w - bmax);
        s += v[it].x + v[it].y + v[it].z + v[it].w;
    }
    #pragma unroll
    for (int o = 32; o > 0; o >>= 1) s += __shfl_xor(s, o);
    if (lane == 0) red[16 + wv] = s;
    __syncthreads();
    float bs = 0.f;
    #pragma unroll
    for (int k = 0; k < 16; ++k) bs += red[16 + k];
    const float inv = 1.f / bs;

    const int q  = m >> 5;
    const int w8 = ((m >> 4) & 1) * 4 + (m & 3);
    const int gl = ((m & 15) >> 2) * 16;
    #pragma unroll
    for (int it = 0; it < 4; ++it) {
        int t = it * 4096 + tid * 4;
        float pv[4] = { v[it].x * inv, v[it].y * inv, v[it].z * inv, v[it].w * inv };
        #pragma unroll
        for (int k = 0; k < 4; ++k) {
            int tok = t + k;
            gateT[(size_t)(tok >> 4) * 2048 + q * 512 + (gl + (tok & 15)) * 8 + w8] = f2bf(pv[k]);
        }
    }
}

// ---------------- mixed[n][i] = sum_j relu(enc@wm[i]^T + bm)[n][j] * gate[n][j] ----------------
// grid 512: tg = bid&3 (XCD-shared tg slice), i = bid>>2. Resident wm panel.
// 2x-unrolled ping-pong: b[s] reloaded inside the MFMA block right after its
// last consumer; G(next) issued right after the block into the idle buffer.
__global__ __launch_bounds__(256)
__attribute__((amdgpu_waves_per_eu(2, 2)))
void k_mix(const unsigned short* __restrict__ wmb,
           const unsigned short* __restrict__ encT,
           const unsigned short* __restrict__ gateT,
           const float* __restrict__ wm_bias,
           unsigned short* __restrict__ mixT) {
    const int bid = blockIdx.x;
    const int tg = bid & 3, i = bid >> 2;
    const int tid = threadIdx.x;
    const int lane = tid & 63, w = tid >> 6;
    const int c = lane & 15, g = lane >> 4;

    const unsigned short* wmi = wmb + (size_t)i * 16384;
    short8 a[8][4];
    #pragma unroll
    for (int jf = 0; jf < 8; ++jf)
        #pragma unroll
        for (int s = 0; s < 4; ++s) {
            a[jf][s] = *(const short8*)(wmi + (jf * 16 + c) * 128 + s * 32 + g * 8);
            asm volatile("" : "+v"(a[jf][s]));
        }
    f32x4 bias4[8];
    #pragma unroll
    for (int f = 0; f < 8; ++f)
        bias4[f] = *(const f32x4*)(wm_bias + i * 128 + f * 16 + 4 * g);

    const int si = i >> 5, ch = (i & 31) >> 3, ei = i & 7;
    const size_t base = (size_t)(tg * 256 + w) * 2048 + lane * 8;
    const unsigned short* encP  = encT + base;
    const unsigned* gateP = (const unsigned*)(gateT + (size_t)(tg * 256 + w) * 2048) + lane * 4;
    unsigned short* mixP = mixT + (size_t)(tg * 256 + w) * 2048 + si * 512 + (ch * 16 + lane) * 8 + ei;

    // prologue: b, GA for rr=0
    short8 b0 = *(const short8*)(encP);
    short8 b1 = *(const short8*)(encP + 512);
    short8 b2 = *(const short8*)(encP + 1024);
    short8 b3 = *(const short8*)(encP + 1536);
    uint4 GA0 = *(const uint4*)(gateP);
    uint4 GA1 = *(const uint4*)(gateP + 256);
    uint4 GA2 = *(const uint4*)(gateP + 512);
    uint4 GA3 = *(const uint4*)(gateP + 768);
    uint4 GB0, GB1, GB2, GB3;

    #define MFMA_BLOCK(NOFF) {                                                      \
        const unsigned short* epn = encP + (size_t)(NOFF) * 2048;                   \
        __builtin_amdgcn_s_setprio(1);                                              \
        _Pragma("unroll")                                                           \
        for (int jf = 0; jf < 8; ++jf)                                              \
            acc[jf] = __builtin_amdgcn_mfma_f32_16x16x32_bf16(a[jf][0], b0, bias4[jf], 0, 0, 0); \
        b0 = *(const short8*)(epn);                                                 \
        _Pragma("unroll")                                                           \
        for (int jf = 0; jf < 8; ++jf)                                              \
            acc[jf] = __builtin_amdgcn_mfma_f32_16x16x32_bf16(a[jf][1], b1, acc[jf], 0, 0, 0); \
        b1 = *(const short8*)(epn + 512);                                           \
        _Pragma("unroll")                                                           \
        for (int jf = 0; jf < 8; ++jf)                                              \
            acc[jf] = __builtin_amdgcn_mfma_f32_16x16x32_bf16(a[jf][2], b2, acc[jf], 0, 0, 0); \
        b2 = *(const short8*)(epn + 1024);                                          \
        _Pragma("unroll")                                                           \
        for (int jf = 0; jf < 8; ++jf)                                              \
            acc[jf] = __builtin_amdgcn_mfma_f32_16x16x32_bf16(a[jf][3], b3, acc[jf], 0, 0, 0); \
        b3 = *(const short8*)(epn + 1536);                                          \
        __builtin_amdgcn_s_setprio(0);                                              \
    }
    #define EPI_ALL(GX0, GX1, GX2, GX3, TOFF) {                                     \
        float p0 = 0.f, p1 = 0.f, p2 = 0.f, p3 = 0.f;                               \
        p0 += fmaxf(acc[0][0], 0.f) * bf2f_lo(GX0.x);                               \
        p1 += fmaxf(acc[0][1], 0.f) * bf2f_hi(GX0.x);                               \
        p2 += fmaxf(acc[0][2], 0.f) * bf2f_lo(GX0.y);                               \
        p3 += fmaxf(acc[0][3], 0.f) * bf2f_hi(GX0.y);                               \
        p0 += fmaxf(acc[1][0], 0.f) * bf2f_lo(GX0.z);                               \
        p1 += fmaxf(acc[1][1], 0.f) * bf2f_hi(GX0.z);                               \
        p2 += fmaxf(acc[1][2], 0.f) * bf2f_lo(GX0.w);                               \
        p3 += fmaxf(acc[1][3], 0.f) * bf2f_hi(GX0.w);                               \
        p0 += fmaxf(acc[2][0], 0.f) * bf2f_lo(GX1.x);                               \
        p1 += fmaxf(acc[2][1], 0.f) * bf2f_hi(GX1.x);                               \
        p2 += fmaxf(acc[2][2], 0.f) * bf2f_lo(GX1.y);                               \
        p3 += fmaxf(acc[2][3], 0.f) * bf2f_hi(GX1.y);                               \
        p0 += fmaxf(acc[3][0], 0.f) * bf2f_lo(GX1.z);                               \
        p1 += fmaxf(acc[3][1], 0.f) * bf2f_hi(GX1.z);                               \
        p2 += fmaxf(acc[3][2], 0.f) * bf2f_lo(GX1.w);                               \
        p3 += fmaxf(acc[3][3], 0.f) * bf2f_hi(GX1.w);                               \
        p0 += fmaxf(acc[4][0], 0.f) * bf2f_lo(GX2.x);                               \
        p1 += fmaxf(acc[4][1], 0.f) * bf2f_hi(GX2.x);                               \
        p2 += fmaxf(acc[4][2], 0.f) * bf2f_lo(GX2.y);                               \
        p3 += fmaxf(acc[4][3], 0.f) * bf2f_hi(GX2.y);                               \
        p0 += fmaxf(acc[5][0], 0.f) * bf2f_lo(GX2.z);                               \
        p1 += fmaxf(acc[5][1], 0.f) * bf2f_hi(GX2.z);                               \
        p2 += fmaxf(acc[5][2], 0.f) * bf2f_lo(GX2.w);                               \
        p3 += fmaxf(acc[5][3], 0.f) * bf2f_hi(GX2.w);                               \
        p0 += fmaxf(acc[6][0], 0.f) * bf2f_lo(GX3.x);                               \
        p1 += fmaxf(acc[6][1], 0.f) * bf2f_hi(GX3.x);                               \
        p2 += fmaxf(acc[6][2], 0.f) * bf2f_lo(GX3.y);                               \
        p3 += fmaxf(acc[6][3], 0.f) * bf2f_hi(GX3.y);                               \
        p0 += fmaxf(acc[7][0], 0.f) * bf2f_lo(GX3.z);                               \
        p1 += fmaxf(acc[7][1], 0.f) * bf2f_hi(GX3.z);                               \
        p2 += fmaxf(acc[7][2], 0.f) * bf2f_lo(GX3.w);                               \
        p3 += fmaxf(acc[7][3], 0.f) * bf2f_hi(GX3.w);                               \
        float p = (p0 + p1) + (p2 + p3);                                            \
        p += __shfl_xor(p, 16);                                                     \
        p += __shfl_xor(p, 32);                                                     \
        if (lane < 16) *(mixP + (size_t)(TOFF) * 2048) = f2bf(p);                   \
    }

    #pragma unroll 1
    for (int rr = 0; rr < 64; rr += 2) {
        f32x4 acc[8];
        // ---- even iter: uses b(rr), GA(rr); b <- rr+1, GB <- rr+1
        MFMA_BLOCK(4 * (rr + 1));
        {
            const unsigned* gpn = gateP + (size_t)(4 * (rr + 1)) * 512;
            GB0 = *(const uint4*)(gpn);
            GB1 = *(const uint4*)(gpn + 256);
            GB2 = *(const uint4*)(gpn + 512);
            GB3 = *(const uint4*)(gpn + 768);
        }
        EPI_ALL(GA0, GA1, GA2, GA3, 4 * rr);
        // ---- odd iter: uses b(rr+1), GB(rr+1); b <- rr+2, GA <- rr+2
        const int nn = (rr < 62) ? rr + 2 : 62;  // clamp (harmless reload)
        MFMA_BLOCK(4 * nn);
        {
            const unsigned* gpn = gateP + (size_t)(4 * nn) * 512;
            GA0 = *(const uint4*)(gpn);
            GA1 = *(const uint4*)(gpn + 256);
            GA2 = *(const uint4*)(gpn + 512);
            GA3 = *(const uint4*)(gpn + 768);
        }
        EPI_ALL(GB0, GB1, GB2, GB3, 4 * (rr + 1));
    }
    #undef MFMA_BLOCK
    #undef EPI_ALL
}

// ---------------- out = relu(mixed @ we1^T + b1 + h0) ----------------
__global__ __launch_bounds__(256)
__attribute__((amdgpu_waves_per_eu(2, 2)))
void k_dec(const unsigned short* __restrict__ we1b,
           const unsigned short* __restrict__ mixT,
           const float* __restrict__ we1_bias,
           const float* __restrict__ h0,
           float* __restrict__ out) {
    const int bid = blockIdx.x;
    const int eb = bid & 7, tg = bid >> 3;
    const int e0 = eb * 128;
    const int tid = threadIdx.x;
    const int lane = tid & 63, w = tid >> 6;
    const int c = lane & 15, g = lane >> 4;

    short8 a[8][4];
    #pragma unroll
    for (int jf = 0; jf < 8; ++jf)
        #pragma unroll
        for (int s = 0; s < 4; ++s) {
            a[jf][s] = *(const short8*)(we1b + (size_t)(e0 + jf * 16 + c) * 128 + s * 32 + g * 8);
            asm volatile("" : "+v"(a[jf][s]));
        }
    fv4 bi[8];
    #pragma unroll
    for (int f = 0; f < 8; ++f)
        bi[f] = *(const fv4*)(we1_bias + e0 + f * 16 + 4 * g);

    #pragma unroll 1
    for (int t = 0; t < 4; ++t) {
        const int tokr = tg * 256 + t * 64 + w * 16 + c;
        const int tile = tg * 16 + t * 4 + w;
        fv4 h[8];
        #pragma unroll
        for (int f = 0; f < 8; ++f)
            h[f] = *(const fv4*)(h0 + (size_t)tokr * 1024 + e0 + f * 16 + 4 * g);
        const unsigned short* mp = mixT + (size_t)tile * 2048 + lane * 8;
        short8 b[4];
        #pragma unroll
        for (int s = 0; s < 4; ++s)
            b[s] = *(const short8*)(mp + s * 512);

        f32x4 acc[8] = {};
        #pragma unroll
        for (int s = 0; s < 4; ++s)
            #pragma unroll
            for (int jf = 0; jf < 8; ++jf)
                acc[jf] = __builtin_amdgcn_mfma_f32_16x16x32_bf16(a[jf][s], b[s], acc[jf], 0, 0, 0);

        #pragma unroll
        for (int f = 0; f < 8; ++f) {
            fv4 o;
            o.x = fmaxf(acc[f][0] + bi[f].x + h[f].x, 0.f);
            o.y = fmaxf(acc[f][1] + bi[f].y + h[f].y, 0.f);
            o.z = fmaxf(acc[f][2] + bi[f].z + h[f].z, 0.f);
            o.w = fmaxf(acc[f][3] + bi[f].w + h[f].w, 0.f);
            *(fv4*)(out + (size_t)tokr * 1024 + e0 + f * 16 + 4 * g) = o;
        }
    }
}

extern "C" void kernel_launch(void* const* d_in, const int* in_sizes, int n_in,
                              void* d_out, int out_size, void* d_ws, size_t ws_size,
                              hipStream_t stream) {
    const float* h0    = (const float*)d_in[0];
    const float* we0_w = (const float*)d_in[1];
    const float* we0_b = (const float*)d_in[2];
    const float* ws_w  = (const float*)d_in[3];
    const float* ws_b  = (const float*)d_in[4];
    const float* wm_w  = (const float*)d_in[5];
    const float* wm_b  = (const float*)d_in[6];
    const float* we1_w = (const float*)d_in[7];
    const float* we1_b = (const float*)d_in[8];
    float* out = (float*)d_out;

    unsigned short* wmb   = (unsigned short*)d_ws;      // 128*128*128
    unsigned short* we0b  = wmb  + 2097152;             // 128*1024
    unsigned short* we1b  = we0b + 131072;              // 1024*128
    unsigned short* wsb   = we1b + 131072;              // 128*128
    unsigned short* encT  = wsb  + 16384;               // 16384*128 (tiled)
    float*          logT  = (float*)(encT + 2097152);   // [128][16384]
    unsigned short* gateT = (unsigned short*)(logT + 2097152); // tiled
    unsigned short* mixT  = gateT + 2097152;            // tiled

    k_convert_all<<<640, 256, 0, stream>>>(wm_w, we0_w, we1_w, ws_w, wmb);
    k_enc<<<512, 256, 0, stream>>>(h0, we0b, wsb, we0_b, ws_b, encT, logT);
    k_softmax0<<<128, 1024, 0, stream>>>(logT, gateT);
    k_mix<<<512, 256, 0, stream>>>(wmb, encT, gateT, wm_b, mixT);
    k_dec<<<512, 256, 0, stream>>>(we1b, mixT, we1_b, h0, out);
}

// Round 8
// 171.523 us; speedup vs baseline: 1.0012x; 1.0012x over previous
//
#include <hip/hip_runtime.h>

// DomDepResidualLayer: out = relu(h0 + (mixed @ we1^T + b1))
//   enc   = h0 @ we0^T + b0                         [16384,128]
//   acts  = relu(einsum('nd,mkd->mnk', enc, wm)+bm) (never materialized)
//   gate  = softmax(enc @ ws^T + bs, axis=0)        [16384,128]
//   mixed[n,i] = sum_j acts[i,n,j]*gate[n,j]        [16384,128]
// v9: k_mix restructured — 4 modules/block (1 reg panel per wave), waves share
// one token tile per iteration, enc+gate(f32) staged via double-buffered LDS
// (reg-stage: load at top, ds_write after epilogue, 1 barrier/iter). Cuts
// enc/gate L2 traffic 4x and replaces ~300cy L2 loads with broadcast ds_reads.

#define N_TOK   16384
#define EMB     1024
#define MDIM    128

typedef __attribute__((ext_vector_type(8))) short   short8;   // 8 bf16 = 1 MFMA frag
typedef __attribute__((ext_vector_type(4))) float   f32x4;
typedef __attribute__((ext_vector_type(4))) float   fv4;
typedef __attribute__((ext_vector_type(4))) unsigned short us4;

static __device__ __forceinline__ unsigned short f2bf(float f) {
    union { float f; unsigned u; } v; v.f = f;
    unsigned r = v.u + 0x7FFFu + ((v.u >> 16) & 1u);   // RNE
    return (unsigned short)(r >> 16);
}

// ---------------- fused fp32 -> bf16 conversion of all weights ----------------
__global__ void k_convert_all(const float* __restrict__ wm_w,
                              const float* __restrict__ we0_w,
                              const float* __restrict__ we1_w,
                              const float* __restrict__ ws_w,
                              unsigned short* __restrict__ dst) {
    const int NFV4 = 593920;
    for (int i = blockIdx.x * blockDim.x + threadIdx.x; i < NFV4;
         i += gridDim.x * blockDim.x) {
        const float* src;
        if (i < 524288)       src = wm_w  + (size_t)i * 4;
        else if (i < 557056)  src = we0_w + (size_t)(i - 524288) * 4;
        else if (i < 589824)  src = we1_w + (size_t)(i - 557056) * 4;
        else                  src = ws_w  + (size_t)(i - 589824) * 4;
        fv4 v = *(const fv4*)src;
        us4 o;
        o.x = f2bf(v.x); o.y = f2bf(v.y); o.z = f2bf(v.z); o.w = f2bf(v.w);
        *(us4*)(dst + (size_t)i * 4) = o;
    }
}

// Fragment-tiled bf16 layout for a [N,128] matrix X (2048 bf16 per 16-tok tile):
//   offset(tok,d) = (tok>>4)*2048 + (d>>5)*512 + (((d&31)>>3)*16 + (tok&15))*8 + (d&7)
// Fragment-tiled f32 gate layout (2048 f32 per tile):
//   offset(tok,j) = (tok>>4)*2048 + (j>>4)*256 + (((j&15)>>2)*16 + (tok&15))*4 + (j&3)

// ---------------- enc = h0 @ we0^T + b0, fused logits^T = enc @ ws^T + bs ----------------
__global__ __launch_bounds__(256) void k_enc(const float* __restrict__ h0,
                                             const unsigned short* __restrict__ we0b,
                                             const unsigned short* __restrict__ wsb,
                                             const float* __restrict__ we0_bias,
                                             const float* __restrict__ ws_bias,
                                             unsigned short* __restrict__ encT,
                                             float* __restrict__ logT) {
    __shared__ unsigned short Wt[128 * 128];
    __shared__ unsigned short Ht[32 * 128];
    __shared__ unsigned short Et[32 * 128];

    const int tid = threadIdx.x;
    const int lane = tid & 63, w = tid >> 6;
    const int c = lane & 15, g = lane >> 4;
    const int wd = w >> 1, wt = w & 1;
    const int t0 = blockIdx.x * 32;

    f32x4 acc[4] = {};
    for (int ks = 0; ks < 8; ++ks) {
        #pragma unroll
        for (int it = 0; it < 8; ++it) {
            int m = it * 256 + tid;
            int row = m >> 4, gc = m & 15;
            short8 v = *(const short8*)(we0b + row * 1024 + ks * 128 + gc * 8);
            *(short8*)&Wt[row * 128 + ((gc ^ (row & 7)) * 8)] = v;
        }
        #pragma unroll
        for (int it = 0; it < 2; ++it) {
            int m = it * 256 + tid;
            int row = m >> 4, gc = m & 15;
            const float* hp = h0 + (size_t)(t0 + row) * 1024 + ks * 128 + gc * 8;
            fv4 v0 = *(const fv4*)hp;
            fv4 v1 = *(const fv4*)(hp + 4);
            short8 ov;
            ov[0] = (short)f2bf(v0.x); ov[1] = (short)f2bf(v0.y);
            ov[2] = (short)f2bf(v0.z); ov[3] = (short)f2bf(v0.w);
            ov[4] = (short)f2bf(v1.x); ov[5] = (short)f2bf(v1.y);
            ov[6] = (short)f2bf(v1.z); ov[7] = (short)f2bf(v1.w);
            *(short8*)&Ht[row * 128 + ((gc ^ (row & 7)) * 8)] = ov;
        }
        __syncthreads();
        #pragma unroll
        for (int s = 0; s < 4; ++s) {
            int gk = s * 4 + g;
            int brow = wt * 16 + c;
            short8 b = *(const short8*)&Ht[brow * 128 + ((gk ^ (brow & 7)) * 8)];
            #pragma unroll
            for (int jf = 0; jf < 4; ++jf) {
                int j = wd * 64 + jf * 16 + c;
                short8 a = *(const short8*)&Wt[j * 128 + ((gk ^ (j & 7)) * 8)];
                acc[jf] = __builtin_amdgcn_mfma_f32_16x16x32_bf16(a, b, acc[jf], 0, 0, 0);
            }
        }
        __syncthreads();
    }
    const int tile = blockIdx.x * 2 + wt;
    const int erow = wt * 16 + c;
    #pragma unroll
    for (int f = 0; f < 4; ++f) {
        int d0 = wd * 64 + f * 16 + 4 * g;
        int s = wd * 2 + (f >> 1);
        int chunk = ((f & 1) ? 2 : 0) + (g >> 1);
        int e = (g & 1) * 4;
        fv4 bi = *(const fv4*)(we0_bias + d0);
        us4 o;
        o.x = f2bf(acc[f][0] + bi.x);
        o.y = f2bf(acc[f][1] + bi.y);
        o.z = f2bf(acc[f][2] + bi.z);
        o.w = f2bf(acc[f][3] + bi.w);
        *(us4*)(encT + (size_t)tile * 2048 + s * 512 + (chunk * 16 + c) * 8 + e) = o;
        int cg = d0 >> 3, off = d0 & 7;
        *(us4*)&Et[erow * 128 + ((cg ^ (erow & 7)) * 8) + off] = o;
    }
    __syncthreads();

    short8 al[4][4];
    #pragma unroll
    for (int jf = 0; jf < 4; ++jf)
        #pragma unroll
        for (int s = 0; s < 4; ++s)
            al[jf][s] = *(const short8*)(wsb + (wd * 64 + jf * 16 + c) * 128 + s * 32 + g * 8);
    short8 bl[4];
    #pragma unroll
    for (int s = 0; s < 4; ++s) {
        int cg2 = s * 4 + g;
        bl[s] = *(const short8*)&Et[erow * 128 + ((cg2 ^ (erow & 7)) * 8)];
    }
    f32x4 acc2[4] = {};
    #pragma unroll
    for (int s = 0; s < 4; ++s)
        #pragma unroll
        for (int jf = 0; jf < 4; ++jf)
            acc2[jf] = __builtin_amdgcn_mfma_f32_16x16x32_bf16(al[jf][s], bl[s], acc2[jf], 0, 0, 0);
    const int tokc = t0 + wt * 16 + c;
    #pragma unroll
    for (int jf = 0; jf < 4; ++jf) {
        int m0 = wd * 64 + jf * 16 + 4 * g;
        fv4 bs = *(const fv4*)(ws_bias + m0);
        logT[(size_t)(m0 + 0) * N_TOK + tokc] = acc2[jf][0] + bs.x;
        logT[(size_t)(m0 + 1) * N_TOK + tokc] = acc2[jf][1] + bs.y;
        logT[(size_t)(m0 + 2) * N_TOK + tokc] = acc2[jf][2] + bs.z;
        logT[(size_t)(m0 + 3) * N_TOK + tokc] = acc2[jf][3] + bs.w;
    }
}

// ---------------- gate = softmax over axis 0, per column m -> gateF (f32, tiled) ----------------
__global__ __launch_bounds__(1024) void k_softmax0(const float* __restrict__ logT,
                                                   float* __restrict__ gateF) {
    __shared__ float red[32];
    const int m = blockIdx.x;
    const int tid = threadIdx.x;
    const int lane = tid & 63, wv = tid >> 6;   // 16 waves
    const float* row = logT + (size_t)m * N_TOK;

    fv4 v[4];
    float vmax = -3.0e38f;
    #pragma unroll
    for (int it = 0; it < 4; ++it) {
        v[it] = *(const fv4*)(row + it * 4096 + tid * 4);
        vmax = fmaxf(vmax, fmaxf(fmaxf(v[it].x, v[it].y), fmaxf(v[it].z, v[it].w)));
    }
    #pragma unroll
    for (int o = 32; o > 0; o >>= 1) vmax = fmaxf(vmax, __shfl_xor(vmax, o));
    if (lane == 0) red[wv] = vmax;
    __syncthreads();
    float bmax = -3.0e38f;
    #pragma unroll
    for (int k = 0; k < 16; ++k) bmax = fmaxf(bmax, red[k]);

    float s = 0.f;
    #pragma unroll
    for (int it = 0; it < 4; ++it) {
        v[it].x = __expf(v[it].x - bmax); v[it].y = __expf(v[it].y - bmax);
        v[it].z = __expf(v[it].z - bmax); v[it].w = __expf(v[it].w - bmax);
        s += v[it].x + v[it].y + v[it].z + v[it].w;
    }
    #pragma unroll
    for (int o = 32; o > 0; o >>= 1) s += __shfl_xor(s, o);
    if (lane == 0) red[16 + wv] = s;
    __syncthreads();
    float bs = 0.f;
    #pragma unroll
    for (int k = 0; k < 16; ++k) bs += red[16 + k];
    const float inv = 1.f / bs;

    // gateF offset(tok, m) = (tok>>4)*2048 + mbase + (tok&15)*4
    const int mbase = ((m >> 4) << 8) + (((m & 15) >> 2) << 6) + (m & 3);
    #pragma unroll
    for (int it = 0; it < 4; ++it) {
        int t = it * 4096 + tid * 4;
        float pv[4] = { v[it].x * inv, v[it].y * inv, v[it].z * inv, v[it].w * inv };
        #pragma unroll
        for (int k = 0; k < 4; ++k) {
            int tok = t + k;
            gateF[(size_t)(tok >> 4) * 2048 + mbase + (tok & 15) * 4] = pv[k];
        }
    }
}

// ---------------- mixed[n][i] = sum_j relu(enc@wm[i]^T + bm)[n][j] * gate[n][j] ----------------
// grid 512 = 32 igroups x 16 tg. Block: 4 waves, wave w owns module i = ig*4+w
// (register panel); all waves share one 16-token tile per iteration from
// double-buffered LDS (enc bf16 4KB + gate f32 8KB per buffer).
__global__ __launch_bounds__(256)
__attribute__((amdgpu_waves_per_eu(2, 2)))
void k_mix(const unsigned short* __restrict__ wmb,
           const unsigned short* __restrict__ encT,
           const float* __restrict__ gateF,
           const float* __restrict__ wm_bias,
           unsigned short* __restrict__ mixT) {
    __shared__ unsigned short ebuf[2][2048];
    __shared__ float gbuf[2][2048];

    const int bid = blockIdx.x;
    const int ig = bid >> 4, tg = bid & 15;
    const int tid = threadIdx.x;
    const int lane = tid & 63, w = tid >> 6;
    const int c = lane & 15, g = lane >> 4;
    const int i = ig * 4 + w;

    const unsigned short* wmi = wmb + (size_t)i * 16384;
    short8 a[8][4];
    #pragma unroll
    for (int jf = 0; jf < 8; ++jf)
        #pragma unroll
        for (int s = 0; s < 4; ++s) {
            a[jf][s] = *(const short8*)(wmi + (jf * 16 + c) * 128 + s * 32 + g * 8);
            asm volatile("" : "+v"(a[jf][s]));
        }
    f32x4 bias4[8];
    #pragma unroll
    for (int f = 0; f < 8; ++f)
        bias4[f] = *(const f32x4*)(wm_bias + i * 128 + f * 16 + 4 * g);

    const int si = i >> 5, ch = (i & 31) >> 3, ei = i & 7;
    const int tile0 = tg * 64;
    unsigned short* mixP = mixT + (size_t)tile0 * 2048 + si * 512 + (ch * 16 + lane) * 8 + ei;

    // prologue: stage tile0 into buffer 0
    {
        uint4 eg = *(const uint4*)(encT + (size_t)tile0 * 2048 + tid * 8);
        uint4 g0 = *(const uint4*)(gateF + (size_t)tile0 * 2048 + tid * 4);
        uint4 g1 = *(const uint4*)(gateF + (size_t)tile0 * 2048 + 1024 + tid * 4);
        *(uint4*)&ebuf[0][tid * 8] = eg;
        *(uint4*)&gbuf[0][tid * 4] = g0;
        *(uint4*)&gbuf[0][1024 + tid * 4] = g1;
    }
    __syncthreads();

    #pragma unroll 1
    for (int t = 0; t < 64; ++t) {
        const int cur = t & 1;
        // issue next-tile global loads first (consumed by ds_write after epilogue)
        uint4 eg = {}, g0 = {}, g1 = {};
        if (t < 63) {
            const size_t nt = (size_t)(tile0 + t + 1) * 2048;
            eg = *(const uint4*)(encT + nt + tid * 8);
            g0 = *(const uint4*)(gateF + nt + tid * 4);
            g1 = *(const uint4*)(gateF + nt + 1024 + tid * 4);
        }

        short8 b0 = *(const short8*)&ebuf[cur][lane * 8];
        short8 b1 = *(const short8*)&ebuf[cur][512 + lane * 8];
        short8 b2 = *(const short8*)&ebuf[cur][1024 + lane * 8];
        short8 b3 = *(const short8*)&ebuf[cur][1536 + lane * 8];

        __builtin_amdgcn_s_setprio(1);
        f32x4 acc[8];
        #pragma unroll
        for (int jf = 0; jf < 8; ++jf)
            acc[jf] = __builtin_amdgcn_mfma_f32_16x16x32_bf16(a[jf][0], b0, bias4[jf], 0, 0, 0);
        #pragma unroll
        for (int jf = 0; jf < 8; ++jf)
            acc[jf] = __builtin_amdgcn_mfma_f32_16x16x32_bf16(a[jf][1], b1, acc[jf], 0, 0, 0);
        #pragma unroll
        for (int jf = 0; jf < 8; ++jf)
            acc[jf] = __builtin_amdgcn_mfma_f32_16x16x32_bf16(a[jf][2], b2, acc[jf], 0, 0, 0);
        #pragma unroll
        for (int jf = 0; jf < 8; ++jf)
            acc[jf] = __builtin_amdgcn_mfma_f32_16x16x32_bf16(a[jf][3], b3, acc[jf], 0, 0, 0);
        __builtin_amdgcn_s_setprio(0);

        float p0 = 0.f, p1 = 0.f, p2 = 0.f, p3 = 0.f;
        #pragma unroll
        for (int f = 0; f < 8; ++f) {
            fv4 G = *(const fv4*)&gbuf[cur][f * 256 + lane * 4];
            p0 += fmaxf(acc[f][0], 0.f) * G.x;
            p1 += fmaxf(acc[f][1], 0.f) * G.y;
            p2 += fmaxf(acc[f][2], 0.f) * G.z;
            p3 += fmaxf(acc[f][3], 0.f) * G.w;
        }
        float p = (p0 + p1) + (p2 + p3);
        p += __shfl_xor(p, 16);
        p += __shfl_xor(p, 32);
        if (lane < 16) *(mixP + (size_t)t * 2048) = f2bf(p);

        if (t < 63) {
            *(uint4*)&ebuf[cur ^ 1][tid * 8] = eg;
            *(uint4*)&gbuf[cur ^ 1][tid * 4] = g0;
            *(uint4*)&gbuf[cur ^ 1][1024 + tid * 4] = g1;
        }
        __syncthreads();
    }
}

// ---------------- out = relu(mixed @ we1^T + b1 + h0) ----------------
__global__ __launch_bounds__(256)
__attribute__((amdgpu_waves_per_eu(2, 2)))
void k_dec(const unsigned short* __restrict__ we1b,
           const unsigned short* __restrict__ mixT,
           const float* __restrict__ we1_bias,
           const float* __restrict__ h0,
           float* __restrict__ out) {
    const int bid = blockIdx.x;
    const int eb = bid & 7, tg = bid >> 3;
    const int e0 = eb * 128;
    const int tid = threadIdx.x;
    const int lane = tid & 63, w = tid >> 6;
    const int c = lane & 15, g = lane >> 4;

    short8 a[8][4];
    #pragma unroll
    for (int jf = 0; jf < 8; ++jf)
        #pragma unroll
        for (int s = 0; s < 4; ++s) {
            a[jf][s] = *(const short8*)(we1b + (size_t)(e0 + jf * 16 + c) * 128 + s * 32 + g * 8);
            asm volatile("" : "+v"(a[jf][s]));
        }
    fv4 bi[8];
    #pragma unroll
    for (int f = 0; f < 8; ++f)
        bi[f] = *(const fv4*)(we1_bias + e0 + f * 16 + 4 * g);

    #pragma unroll 1
    for (int t = 0; t < 4; ++t) {
        const int tokr = tg * 256 + t * 64 + w * 16 + c;
        const int tile = tg * 16 + t * 4 + w;
        fv4 h[8];
        #pragma unroll
        for (int f = 0; f < 8; ++f)
            h[f] = *(const fv4*)(h0 + (size_t)tokr * 1024 + e0 + f * 16 + 4 * g);
        const unsigned short* mp = mixT + (size_t)tile * 2048 + lane * 8;
        short8 b[4];
        #pragma unroll
        for (int s = 0; s < 4; ++s)
            b[s] = *(const short8*)(mp + s * 512);

        f32x4 acc[8] = {};
        #pragma unroll
        for (int s = 0; s < 4; ++s)
            #pragma unroll
            for (int jf = 0; jf < 8; ++jf)
                acc[jf] = __builtin_amdgcn_mfma_f32_16x16x32_bf16(a[jf][s], b[s], acc[jf], 0, 0, 0);

        #pragma unroll
        for (int f = 0; f < 8; ++f) {
            fv4 o;
            o.x = fmaxf(acc[f][0] + bi[f].x + h[f].x, 0.f);
            o.y = fmaxf(acc[f][1] + bi[f].y + h[f].y, 0.f);
            o.z = fmaxf(acc[f][2] + bi[f].z + h[f].z, 0.f);
            o.w = fmaxf(acc[f][3] + bi[f].w + h[f].w, 0.f);
            *(fv4*)(out + (size_t)tokr * 1024 + e0 + f * 16 + 4 * g) = o;
        }
    }
}

extern "C" void kernel_launch(void* const* d_in, const int* in_sizes, int n_in,
                              void* d_out, int out_size, void* d_ws, size_t ws_size,
                              hipStream_t stream) {
    const float* h0    = (const float*)d_in[0];
    const float* we0_w = (const float*)d_in[1];
    const float* we0_b = (const float*)d_in[2];
    const float* ws_w  = (const float*)d_in[3];
    const float* ws_b  = (const float*)d_in[4];
    const float* wm_w  = (const float*)d_in[5];
    const float* wm_b  = (const float*)d_in[6];
    const float* we1_w = (const float*)d_in[7];
    const float* we1_b = (const float*)d_in[8];
    float* out = (float*)d_out;

    unsigned short* wmb   = (unsigned short*)d_ws;      // 128*128*128 bf16
    unsigned short* we0b  = wmb  + 2097152;             // 128*1024
    unsigned short* we1b  = we0b + 131072;              // 1024*128
    unsigned short* wsb   = we1b + 131072;              // 128*128
    unsigned short* encT  = wsb  + 16384;               // 16384*128 bf16 (tiled)
    float*          logT  = (float*)(encT + 2097152);   // [128][16384] f32 (8MB)
    float*          gateF = logT + 2097152;             // 16384*128 f32 (tiled, 8MB)
    unsigned short* mixT  = (unsigned short*)logT;      // overlays dead logT (4MB)

    k_convert_all<<<640, 256, 0, stream>>>(wm_w, we0_w, we1_w, ws_w, wmb);
    k_enc<<<512, 256, 0, stream>>>(h0, we0b, wsb, we0_b, ws_b, encT, logT);
    k_softmax0<<<128, 1024, 0, stream>>>(logT, gateF);
    k_mix<<<512, 256, 0, stream>>>(wmb, encT, gateF, wm_b, mixT);
    k_dec<<<512, 256, 0, stream>>>(we1b, mixT, we1_b, h0, out);
}

// Round 9
// 168.591 us; speedup vs baseline: 1.0187x; 1.0174x over previous
//
#include <hip/hip_runtime.h>

// DomDepResidualLayer: out = relu(h0 + (mixed @ we1^T + b1))
//   enc   = h0 @ we0^T + b0                         [16384,128]
//   acts  = relu(einsum('nd,mkd->mnk', enc, wm)+bm) (never materialized)
//   gate  = softmax(enc @ ws^T + bs, axis=0)        [16384,128]
//   mixed[n,i] = sum_j acts[i,n,j]*gate[n,j]        [16384,128]
// v10: k_mix vmem fully inline-asm with counted s_waitcnt vmcnt(N) (T3/T4):
// per half-iter = 4 b-loads(t+2) + 1 store(t) + 4 g-loads(t+1); waits
// vmcnt(14) before MFMA, vmcnt(4) before epilogue; sched_barrier after each.
// Compiler can no longer collapse the pipeline at the back-edge.

#define N_TOK   16384
#define EMB     1024
#define MDIM    128

typedef __attribute__((ext_vector_type(8))) short   short8;   // 8 bf16 = 1 MFMA frag
typedef __attribute__((ext_vector_type(4))) float   f32x4;
typedef __attribute__((ext_vector_type(4))) float   fv4;
typedef __attribute__((ext_vector_type(4))) unsigned short us4;

static __device__ __forceinline__ unsigned short f2bf(float f) {
    union { float f; unsigned u; } v; v.f = f;
    unsigned r = v.u + 0x7FFFu + ((v.u >> 16) & 1u);   // RNE
    return (unsigned short)(r >> 16);
}
static __device__ __forceinline__ float bf2f_lo(unsigned u) {
    union { unsigned u; float f; } v; v.u = u << 16; return v.f;
}
static __device__ __forceinline__ float bf2f_hi(unsigned u) {
    union { unsigned u; float f; } v; v.u = u & 0xffff0000u; return v.f;
}

// ---------------- fused fp32 -> bf16 conversion of all weights ----------------
__global__ void k_convert_all(const float* __restrict__ wm_w,
                              const float* __restrict__ we0_w,
                              const float* __restrict__ we1_w,
                              const float* __restrict__ ws_w,
                              unsigned short* __restrict__ dst) {
    const int NFV4 = 593920;
    for (int i = blockIdx.x * blockDim.x + threadIdx.x; i < NFV4;
         i += gridDim.x * blockDim.x) {
        const float* src;
        if (i < 524288)       src = wm_w  + (size_t)i * 4;
        else if (i < 557056)  src = we0_w + (size_t)(i - 524288) * 4;
        else if (i < 589824)  src = we1_w + (size_t)(i - 557056) * 4;
        else                  src = ws_w  + (size_t)(i - 589824) * 4;
        fv4 v = *(const fv4*)src;
        us4 o;
        o.x = f2bf(v.x); o.y = f2bf(v.y); o.z = f2bf(v.z); o.w = f2bf(v.w);
        *(us4*)(dst + (size_t)i * 4) = o;
    }
}

// Fragment-tiled bf16 layout for a [N,128] matrix X (2048 bf16 per 16-tok tile):
//   offset(tok,d) = (tok>>4)*2048 + (d>>5)*512 + (((d&31)>>3)*16 + (tok&15))*8 + (d&7)

// ---------------- enc = h0 @ we0^T + b0, fused logits^T = enc @ ws^T + bs ----------------
__global__ __launch_bounds__(256) void k_enc(const float* __restrict__ h0,
                                             const unsigned short* __restrict__ we0b,
                                             const unsigned short* __restrict__ wsb,
                                             const float* __restrict__ we0_bias,
                                             const float* __restrict__ ws_bias,
                                             unsigned short* __restrict__ encT,
                                             float* __restrict__ logT) {
    __shared__ unsigned short Wt[128 * 128];
    __shared__ unsigned short Ht[32 * 128];
    __shared__ unsigned short Et[32 * 128];

    const int tid = threadIdx.x;
    const int lane = tid & 63, w = tid >> 6;
    const int c = lane & 15, g = lane >> 4;
    const int wd = w >> 1, wt = w & 1;
    const int t0 = blockIdx.x * 32;

    f32x4 acc[4] = {};
    for (int ks = 0; ks < 8; ++ks) {
        #pragma unroll
        for (int it = 0; it < 8; ++it) {
            int m = it * 256 + tid;
            int row = m >> 4, gc = m & 15;
            short8 v = *(const short8*)(we0b + row * 1024 + ks * 128 + gc * 8);
            *(short8*)&Wt[row * 128 + ((gc ^ (row & 7)) * 8)] = v;
        }
        #pragma unroll
        for (int it = 0; it < 2; ++it) {
            int m = it * 256 + tid;
            int row = m >> 4, gc = m & 15;
            const float* hp = h0 + (size_t)(t0 + row) * 1024 + ks * 128 + gc * 8;
            fv4 v0 = *(const fv4*)hp;
            fv4 v1 = *(const fv4*)(hp + 4);
            short8 ov;
            ov[0] = (short)f2bf(v0.x); ov[1] = (short)f2bf(v0.y);
            ov[2] = (short)f2bf(v0.z); ov[3] = (short)f2bf(v0.w);
            ov[4] = (short)f2bf(v1.x); ov[5] = (short)f2bf(v1.y);
            ov[6] = (short)f2bf(v1.z); ov[7] = (short)f2bf(v1.w);
            *(short8*)&Ht[row * 128 + ((gc ^ (row & 7)) * 8)] = ov;
        }
        __syncthreads();
        #pragma unroll
        for (int s = 0; s < 4; ++s) {
            int gk = s * 4 + g;
            int brow = wt * 16 + c;
            short8 b = *(const short8*)&Ht[brow * 128 + ((gk ^ (brow & 7)) * 8)];
            #pragma unroll
            for (int jf = 0; jf < 4; ++jf) {
                int j = wd * 64 + jf * 16 + c;
                short8 a = *(const short8*)&Wt[j * 128 + ((gk ^ (j & 7)) * 8)];
                acc[jf] = __builtin_amdgcn_mfma_f32_16x16x32_bf16(a, b, acc[jf], 0, 0, 0);
            }
        }
        __syncthreads();
    }
    const int tile = blockIdx.x * 2 + wt;
    const int erow = wt * 16 + c;
    #pragma unroll
    for (int f = 0; f < 4; ++f) {
        int d0 = wd * 64 + f * 16 + 4 * g;
        int s = wd * 2 + (f >> 1);
        int chunk = ((f & 1) ? 2 : 0) + (g >> 1);
        int e = (g & 1) * 4;
        fv4 bi = *(const fv4*)(we0_bias + d0);
        us4 o;
        o.x = f2bf(acc[f][0] + bi.x);
        o.y = f2bf(acc[f][1] + bi.y);
        o.z = f2bf(acc[f][2] + bi.z);
        o.w = f2bf(acc[f][3] + bi.w);
        *(us4*)(encT + (size_t)tile * 2048 + s * 512 + (chunk * 16 + c) * 8 + e) = o;
        int cg = d0 >> 3, off = d0 & 7;
        *(us4*)&Et[erow * 128 + ((cg ^ (erow & 7)) * 8) + off] = o;
    }
    __syncthreads();

    short8 al[4][4];
    #pragma unroll
    for (int jf = 0; jf < 4; ++jf)
        #pragma unroll
        for (int s = 0; s < 4; ++s)
            al[jf][s] = *(const short8*)(wsb + (wd * 64 + jf * 16 + c) * 128 + s * 32 + g * 8);
    short8 bl[4];
    #pragma unroll
    for (int s = 0; s < 4; ++s) {
        int cg2 = s * 4 + g;
        bl[s] = *(const short8*)&Et[erow * 128 + ((cg2 ^ (erow & 7)) * 8)];
    }
    f32x4 acc2[4] = {};
    #pragma unroll
    for (int s = 0; s < 4; ++s)
        #pragma unroll
        for (int jf = 0; jf < 4; ++jf)
            acc2[jf] = __builtin_amdgcn_mfma_f32_16x16x32_bf16(al[jf][s], bl[s], acc2[jf], 0, 0, 0);
    const int tokc = t0 + wt * 16 + c;
    #pragma unroll
    for (int jf = 0; jf < 4; ++jf) {
        int m0 = wd * 64 + jf * 16 + 4 * g;
        fv4 bs = *(const fv4*)(ws_bias + m0);
        logT[(size_t)(m0 + 0) * N_TOK + tokc] = acc2[jf][0] + bs.x;
        logT[(size_t)(m0 + 1) * N_TOK + tokc] = acc2[jf][1] + bs.y;
        logT[(size_t)(m0 + 2) * N_TOK + tokc] = acc2[jf][2] + bs.z;
        logT[(size_t)(m0 + 3) * N_TOK + tokc] = acc2[jf][3] + bs.w;
    }
}

// ---------------- gate = softmax over axis 0, per column m (bf16, tiled) ----------------
__global__ __launch_bounds__(1024) void k_softmax0(const float* __restrict__ logT,
                                                   unsigned short* __restrict__ gateT) {
    __shared__ float red[32];
    const int m = blockIdx.x;
    const int tid = threadIdx.x;
    const int lane = tid & 63, wv = tid >> 6;   // 16 waves
    const float* row = logT + (size_t)m * N_TOK;

    fv4 v[4];
    float vmax = -3.0e38f;
    #pragma unroll
    for (int it = 0; it < 4; ++it) {
        v[it] = *(const fv4*)(row + it * 4096 + tid * 4);
        vmax = fmaxf(vmax, fmaxf(fmaxf(v[it].x, v[it].y), fmaxf(v[it].z, v[it].w)));
    }
    #pragma unroll
    for (int o = 32; o > 0; o >>= 1) vmax = fmaxf(vmax, __shfl_xor(vmax, o));
    if (lane == 0) red[wv] = vmax;
    __syncthreads();
    float bmax = -3.0e38f;
    #pragma unroll
    for (int k = 0; k < 16; ++k) bmax = fmaxf(bmax, red[k]);

    float s = 0.f;
    #pragma unroll
    for (int it = 0; it < 4; ++it) {
        v[it].x = __expf(v[it].x - bmax); v[it].y = __expf(v[it].y - bmax);
        v[it].z = __expf(v[it].z - bmax); v[it].w = __expf(v[it].w - bmax);
        s += v[it].x + v[it].y + v[it].z + v[it].w;
    }
    #pragma unroll
    for (int o = 32; o > 0; o >>= 1) s += __shfl_xor(s, o);
    if (lane == 0) red[16 + wv] = s;
    __syncthreads();
    float bs = 0.f;
    #pragma unroll
    for (int k = 0; k < 16; ++k) bs += red[16 + k];
    const float inv = 1.f / bs;

    const int q  = m >> 5;
    const int w8 = ((m >> 4) & 1) * 4 + (m & 3);
    const int gl = ((m & 15) >> 2) * 16;
    #pragma unroll
    for (int it = 0; it < 4; ++it) {
        int t = it * 4096 + tid * 4;
        float pv[4] = { v[it].x * inv, v[it].y * inv, v[it].z * inv, v[it].w * inv };
        #pragma unroll
        for (int k = 0; k < 4; ++k) {
            int tok = t + k;
            gateT[(size_t)(tok >> 4) * 2048 + q * 512 + (gl + (tok & 15)) * 8 + w8] = f2bf(pv[k]);
        }
    }
}

// ---------------- k_mix: asm-pipelined ----------------
#define GLOAD(dst, base, imm)                                           \
    asm volatile("global_load_dwordx4 %0, %1, off offset:" imm          \
                 : "=v"(dst) : "v"(base))
#define VMW(n) do { asm volatile("s_waitcnt vmcnt(" n ")" ::: "memory");\
                    __builtin_amdgcn_sched_barrier(0); } while (0)

__global__ __launch_bounds__(256)
__attribute__((amdgpu_waves_per_eu(2, 2)))
void k_mix(const unsigned short* __restrict__ wmb,
           const unsigned short* __restrict__ encT,
           const unsigned short* __restrict__ gateT,
           const float* __restrict__ wm_bias,
           unsigned short* __restrict__ mixT) {
    const int bid = blockIdx.x;
    const int tg = bid & 3, i = bid >> 2;
    const int tid = threadIdx.x;
    const int lane = tid & 63, w = tid >> 6;
    const int c = lane & 15, g = lane >> 4;

    const unsigned short* wmi = wmb + (size_t)i * 16384;
    short8 a[8][4];
    #pragma unroll
    for (int jf = 0; jf < 8; ++jf)
        #pragma unroll
        for (int s = 0; s < 4; ++s) {
            a[jf][s] = *(const short8*)(wmi + (jf * 16 + c) * 128 + s * 32 + g * 8);
            asm volatile("" : "+v"(a[jf][s]));
        }
    f32x4 bias4[8];
    #pragma unroll
    for (int f = 0; f < 8; ++f) {
        bias4[f] = *(const f32x4*)(wm_bias + i * 128 + f * 16 + 4 * g);
        asm volatile("" : "+v"(bias4[f]));
    }

    const int si = i >> 5, ch = (i & 31) >> 3, ei = i & 7;
    // per-t stride = 4 tiles = 16384 bytes
    const char* encB  = (const char*)(encT  + (size_t)(tg * 256 + w) * 2048) + lane * 16;
    const char* gateB = (const char*)(gateT + (size_t)(tg * 256 + w) * 2048) + lane * 16;
    unsigned short* mixB = mixT + (size_t)(tg * 256 + w) * 2048 + si * 512 + (ch * 16 + lane) * 8 + ei;

    uint4 bA0, bA1, bA2, bA3, bB0, bB1, bB2, bB3, g0, g1, g2, g3, dmy;
    // prologue: bA(0), bB(1), 6 dummies, g(0)  -> 14 ops follow bA(0)
    GLOAD(bA0, encB, "0"); GLOAD(bA1, encB, "1024");
    GLOAD(bA2, encB, "2048"); GLOAD(bA3, encB, "3072");
    { const char* e1 = encB + 16384;
      GLOAD(bB0, e1, "0"); GLOAD(bB1, e1, "1024");
      GLOAD(bB2, e1, "2048"); GLOAD(bB3, e1, "3072"); }
    GLOAD(dmy, encB, "0"); GLOAD(dmy, encB, "0"); GLOAD(dmy, encB, "0");
    GLOAD(dmy, encB, "0"); GLOAD(dmy, encB, "0"); GLOAD(dmy, encB, "0");
    GLOAD(g0, gateB, "0"); GLOAD(g1, gateB, "1024");
    GLOAD(g2, gateB, "2048"); GLOAD(g3, gateB, "3072");

    #define AS8(x) __builtin_bit_cast(short8, x)
    #define MFMAB(B0, B1, B2, B3)                                              \
        {                                                                      \
            short8 vb0 = AS8(B0), vb1 = AS8(B1), vb2 = AS8(B2), vb3 = AS8(B3); \
            __builtin_amdgcn_s_setprio(1);                                     \
            _Pragma("unroll")                                                  \
            for (int jf = 0; jf < 8; ++jf)                                     \
                acc[jf] = __builtin_amdgcn_mfma_f32_16x16x32_bf16(a[jf][0], vb0, bias4[jf], 0, 0, 0); \
            _Pragma("unroll")                                                  \
            for (int jf = 0; jf < 8; ++jf)                                     \
                acc[jf] = __builtin_amdgcn_mfma_f32_16x16x32_bf16(a[jf][1], vb1, acc[jf], 0, 0, 0); \
            _Pragma("unroll")                                                  \
            for (int jf = 0; jf < 8; ++jf)                                     \
                acc[jf] = __builtin_amdgcn_mfma_f32_16x16x32_bf16(a[jf][2], vb2, acc[jf], 0, 0, 0); \
            _Pragma("unroll")                                                  \
            for (int jf = 0; jf < 8; ++jf)                                     \
                acc[jf] = __builtin_amdgcn_mfma_f32_16x16x32_bf16(a[jf][3], vb3, acc[jf], 0, 0, 0); \
            __builtin_amdgcn_s_setprio(0);                                     \
        }
    #define EPI_ST(TT)                                                         \
        {                                                                      \
            float p0 = 0.f, p1 = 0.f, p2 = 0.f, p3 = 0.f;                      \
            p0 += fmaxf(acc[0][0], 0.f) * bf2f_lo(g0.x);                       \
            p1 += fmaxf(acc[0][1], 0.f) * bf2f_hi(g0.x);                       \
            p2 += fmaxf(acc[0][2], 0.f) * bf2f_lo(g0.y);                       \
            p3 += fmaxf(acc[0][3], 0.f) * bf2f_hi(g0.y);                       \
            p0 += fmaxf(acc[1][0], 0.f) * bf2f_lo(g0.z);                       \
            p1 += fmaxf(acc[1][1], 0.f) * bf2f_hi(g0.z);                       \
            p2 += fmaxf(acc[1][2], 0.f) * bf2f_lo(g0.w);                       \
            p3 += fmaxf(acc[1][3], 0.f) * bf2f_hi(g0.w);                       \
            p0 += fmaxf(acc[2][0], 0.f) * bf2f_lo(g1.x);                       \
            p1 += fmaxf(acc[2][1], 0.f) * bf2f_hi(g1.x);                       \
            p2 += fmaxf(acc[2][2], 0.f) * bf2f_lo(g1.y);                       \
            p3 += fmaxf(acc[2][3], 0.f) * bf2f_hi(g1.y);                       \
            p0 += fmaxf(acc[3][0], 0.f) * bf2f_lo(g1.z);                       \
            p1 += fmaxf(acc[3][1], 0.f) * bf2f_hi(g1.z);                       \
            p2 += fmaxf(acc[3][2], 0.f) * bf2f_lo(g1.w);                       \
            p3 += fmaxf(acc[3][3], 0.f) * bf2f_hi(g1.w);                       \
            p0 += fmaxf(acc[4][0], 0.f) * bf2f_lo(g2.x);                       \
            p1 += fmaxf(acc[4][1], 0.f) * bf2f_hi(g2.x);                       \
            p2 += fmaxf(acc[4][2], 0.f) * bf2f_lo(g2.y);                       \
            p3 += fmaxf(acc[4][3], 0.f) * bf2f_hi(g2.y);                       \
            p0 += fmaxf(acc[5][0], 0.f) * bf2f_lo(g2.z);                       \
            p1 += fmaxf(acc[5][1], 0.f) * bf2f_hi(g2.z);                       \
            p2 += fmaxf(acc[5][2], 0.f) * bf2f_lo(g2.w);                       \
            p3 += fmaxf(acc[5][3], 0.f) * bf2f_hi(g2.w);                       \
            p0 += fmaxf(acc[6][0], 0.f) * bf2f_lo(g3.x);                       \
            p1 += fmaxf(acc[6][1], 0.f) * bf2f_hi(g3.x);                       \
            p2 += fmaxf(acc[6][2], 0.f) * bf2f_lo(g3.y);                       \
            p3 += fmaxf(acc[6][3], 0.f) * bf2f_hi(g3.y);                       \
            p0 += fmaxf(acc[7][0], 0.f) * bf2f_lo(g3.z);                       \
            p1 += fmaxf(acc[7][1], 0.f) * bf2f_hi(g3.z);                       \
            p2 += fmaxf(acc[7][2], 0.f) * bf2f_lo(g3.w);                       \
            p3 += fmaxf(acc[7][3], 0.f) * bf2f_hi(g3.w);                       \
            float p = (p0 + p1) + (p2 + p3);                                   \
            p += __shfl_xor(p, 16);                                            \
            p += __shfl_xor(p, 32);                                            \
            unsigned pv = f2bf(p);                                             \
            if (lane < 16)                                                     \
                asm volatile("global_store_short %0, %1, off"                  \
                             :: "v"(mixB + (size_t)(TT) * 8192), "v"(pv)       \
                             : "memory");                                      \
        }
    #define HALF(TT, B0, B1, B2, B3)                                           \
        {                                                                      \
            VMW("14");                                                         \
            f32x4 acc[8];                                                      \
            MFMAB(B0, B1, B2, B3);                                             \
            { int tb = (TT) + 2 < 64 ? (TT) + 2 : 63;                          \
              const char* eb = encB + (size_t)tb * 16384;                      \
              GLOAD(B0, eb, "0"); GLOAD(B1, eb, "1024");                       \
              GLOAD(B2, eb, "2048"); GLOAD(B3, eb, "3072"); }                  \
            VMW("4");                                                          \
            EPI_ST(TT);                                                        \
            { int tn = (TT) + 1 < 64 ? (TT) + 1 : 63;                          \
              const char* gb = gateB + (size_t)tn * 16384;                     \
              GLOAD(g0, gb, "0"); GLOAD(g1, gb, "1024");                       \
              GLOAD(g2, gb, "2048"); GLOAD(g3, gb, "3072"); }                  \
        }

    #pragma unroll 1
    for (int t = 0; t < 64; t += 2) {
        HALF(t,     bA0, bA1, bA2, bA3);
        HALF(t + 1, bB0, bB1, bB2, bB3);
    }
    #undef HALF
    #undef EPI_ST
    #undef MFMAB
    #undef AS8
}

// ---------------- out = relu(mixed @ we1^T + b1 + h0) ----------------
__global__ __launch_bounds__(256)
__attribute__((amdgpu_waves_per_eu(2, 2)))
void k_dec(const unsigned short* __restrict__ we1b,
           const unsigned short* __restrict__ mixT,
           const float* __restrict__ we1_bias,
           const float* __restrict__ h0,
           float* __restrict__ out) {
    const int bid = blockIdx.x;
    const int eb = bid & 7, tg = bid >> 3;
    const int e0 = eb * 128;
    const int tid = threadIdx.x;
    const int lane = tid & 63, w = tid >> 6;
    const int c = lane & 15, g = lane >> 4;

    short8 a[8][4];
    #pragma unroll
    for (int jf = 0; jf < 8; ++jf)
        #pragma unroll
        for (int s = 0; s < 4; ++s) {
            a[jf][s] = *(const short8*)(we1b + (size_t)(e0 + jf * 16 + c) * 128 + s * 32 + g * 8);
            asm volatile("" : "+v"(a[jf][s]));
        }
    fv4 bi[8];
    #pragma unroll
    for (int f = 0; f < 8; ++f)
        bi[f] = *(const fv4*)(we1_bias + e0 + f * 16 + 4 * g);

    #pragma unroll 1
    for (int t = 0; t < 4; ++t) {
        const int tokr = tg * 256 + t * 64 + w * 16 + c;
        const int tile = tg * 16 + t * 4 + w;
        fv4 h[8];
        #pragma unroll
        for (int f = 0; f < 8; ++f)
            h[f] = *(const fv4*)(h0 + (size_t)tokr * 1024 + e0 + f * 16 + 4 * g);
        const unsigned short* mp = mixT + (size_t)tile * 2048 + lane * 8;
        short8 b[4];
        #pragma unroll
        for (int s = 0; s < 4; ++s)
            b[s] = *(const short8*)(mp + s * 512);

        f32x4 acc[8] = {};
        #pragma unroll
        for (int s = 0; s < 4; ++s)
            #pragma unroll
            for (int jf = 0; jf < 8; ++jf)
                acc[jf] = __builtin_amdgcn_mfma_f32_16x16x32_bf16(a[jf][s], b[s], acc[jf], 0, 0, 0);

        #pragma unroll
        for (int f = 0; f < 8; ++f) {
            fv4 o;
            o.x = fmaxf(acc[f][0] + bi[f].x + h[f].x, 0.f);
            o.y = fmaxf(acc[f][1] + bi[f].y + h[f].y, 0.f);
            o.z = fmaxf(acc[f][2] + bi[f].z + h[f].z, 0.f);
            o.w = fmaxf(acc[f][3] + bi[f].w + h[f].w, 0.f);
            *(fv4*)(out + (size_t)tokr * 1024 + e0 + f * 16 + 4 * g) = o;
        }
    }
}

extern "C" void kernel_launch(void* const* d_in, const int* in_sizes, int n_in,
                              void* d_out, int out_size, void* d_ws, size_t ws_size,
                              hipStream_t stream) {
    const float* h0    = (const float*)d_in[0];
    const float* we0_w = (const float*)d_in[1];
    const float* we0_b = (const float*)d_in[2];
    const float* ws_w  = (const float*)d_in[3];
    const float* ws_b  = (const float*)d_in[4];
    const float* wm_w  = (const float*)d_in[5];
    const float* wm_b  = (const float*)d_in[6];
    const float* we1_w = (const float*)d_in[7];
    const float* we1_b = (const float*)d_in[8];
    float* out = (float*)d_out;

    unsigned short* wmb   = (unsigned short*)d_ws;      // 128*128*128
    unsigned short* we0b  = wmb  + 2097152;             // 128*1024
    unsigned short* we1b  = we0b + 131072;              // 1024*128
    unsigned short* wsb   = we1b + 131072;              // 128*128
    unsigned short* encT  = wsb  + 16384;               // 16384*128 (tiled)
    float*          logT  = (float*)(encT + 2097152);   // [128][16384]
    unsigned short* gateT = (unsigned short*)(logT + 2097152); // tiled bf16
    unsigned short* mixT  = gateT + 2097152;            // tiled

    k_convert_all<<<640, 256, 0, stream>>>(wm_w, we0_w, we1_w, ws_w, wmb);
    k_enc<<<512, 256, 0, stream>>>(h0, we0b, wsb, we0_b, ws_b, encT, logT);
    k_softmax0<<<128, 1024, 0, stream>>>(logT, gateT);
    k_mix<<<512, 256, 0, stream>>>(wmb, encT, gateT, wm_b, mixT);
    k_dec<<<512, 256, 0, stream>>>(we1b, mixT, we1_b, h0, out);
}

// Round 10
// 158.281 us; speedup vs baseline: 1.0850x; 1.0651x over previous
//
#include <hip/hip_runtime.h>

// DomDepResidualLayer: out = relu(h0 + (mixed @ we1^T + b1))
//   enc   = h0 @ we0^T + b0                         [16384,128]
//   acts  = relu(einsum('nd,mkd->mnk', enc, wm)+bm) (never materialized)
//   gate  = softmax(enc @ ws^T + bs, axis=0)        [16384,128]
//   mixed[n,i] = sum_j acts[i,n,j]*gate[n,j]        [16384,128]
// v11: k_mix in FP8 (e4m3): wm panel 64 VGPRs + enc fp8 -> ~160 regs ->
// 3 waves/SIMD (grid 768 = 128 modules x 6 parts). Same MFMA rate as bf16,
// +50% TLP to co-fill matrix+VALU pipes, enc bytes halved. Gate stays bf16
// (softmax values ~6e-5 underflow e4m3).

#define N_TOK   16384
#define EMB     1024
#define MDIM    128

typedef __attribute__((ext_vector_type(8))) short   short8;   // 8 bf16 = 1 bf16 MFMA frag
typedef __attribute__((ext_vector_type(4))) float   f32x4;
typedef __attribute__((ext_vector_type(4))) float   fv4;
typedef __attribute__((ext_vector_type(4))) unsigned short us4;

static __device__ __forceinline__ unsigned short f2bf(float f) {
    union { float f; unsigned u; } v; v.f = f;
    unsigned r = v.u + 0x7FFFu + ((v.u >> 16) & 1u);   // RNE
    return (unsigned short)(r >> 16);
}
static __device__ __forceinline__ float bf2f_lo(unsigned u) {
    union { unsigned u; float f; } v; v.u = u << 16; return v.f;
}
static __device__ __forceinline__ float bf2f_hi(unsigned u) {
    union { unsigned u; float f; } v; v.u = u & 0xffff0000u; return v.f;
}

// ---------------- fused weight conversion: wm -> fp8, we0/we1/ws -> bf16 ----------------
__global__ void k_convert_all(const float* __restrict__ wm_w,
                              const float* __restrict__ we0_w,
                              const float* __restrict__ we1_w,
                              const float* __restrict__ ws_w,
                              unsigned* __restrict__ wmf8,
                              unsigned short* __restrict__ bf16dst) {
    const int N = 524288 + 36864;
    for (int i = blockIdx.x * blockDim.x + threadIdx.x; i < N;
         i += gridDim.x * blockDim.x) {
        if (i < 524288) {                       // wm -> fp8 e4m3, 4 vals per u32
            fv4 v = *(const fv4*)(wm_w + (size_t)i * 4);
            int pk = __builtin_amdgcn_cvt_pk_fp8_f32(v.x, v.y, 0, false);
            pk = __builtin_amdgcn_cvt_pk_fp8_f32(v.z, v.w, pk, true);
            wmf8[i] = (unsigned)pk;
        } else {                                // we0|we1|ws -> bf16
            int j = i - 524288;
            const float* src;
            if (j < 32768)      src = we0_w + (size_t)j * 4;
            else if (j < 65536) src = we1_w + (size_t)(j - 32768) * 4;
            else                src = ws_w  + (size_t)(j - 65536) * 4;
            fv4 v = *(const fv4*)src;
            us4 o;
            o.x = f2bf(v.x); o.y = f2bf(v.y); o.z = f2bf(v.z); o.w = f2bf(v.w);
            *(us4*)(bf16dst + (size_t)j * 4) = o;
        }
    }
}

// encF8 fp8 tile layout (2048 B per 16-tok tile), per-lane-contiguous:
//   byte(tok, d) = tile*2048 + (((d&31)>>3)*16 + tok)*32 + (d>>5)*8 + (d&7)
//   -> k_mix lane l reads its 32 k-bytes at [tile*2048 + l*32, +32)
// gateT bf16 tiled as before:
//   elem(tok, j) = tile*2048 + (j>>5)*512 + (((j&31)>>4)*... (v3 layout, unchanged)

// ---------------- enc = h0 @ we0^T + b0 (fp8 out), fused logits = enc @ ws^T + bs ----------------
__global__ __launch_bounds__(256) void k_enc(const float* __restrict__ h0,
                                             const unsigned short* __restrict__ we0b,
                                             const unsigned short* __restrict__ wsb,
                                             const float* __restrict__ we0_bias,
                                             const float* __restrict__ ws_bias,
                                             unsigned char* __restrict__ encF8,
                                             float* __restrict__ logT) {
    __shared__ unsigned short Wt[128 * 128];
    __shared__ unsigned short Ht[32 * 128];
    __shared__ unsigned short Et[32 * 128];

    const int tid = threadIdx.x;
    const int lane = tid & 63, w = tid >> 6;
    const int c = lane & 15, g = lane >> 4;
    const int wd = w >> 1, wt = w & 1;
    const int t0 = blockIdx.x * 32;

    f32x4 acc[4] = {};
    for (int ks = 0; ks < 8; ++ks) {
        #pragma unroll
        for (int it = 0; it < 8; ++it) {
            int m = it * 256 + tid;
            int row = m >> 4, gc = m & 15;
            short8 v = *(const short8*)(we0b + row * 1024 + ks * 128 + gc * 8);
            *(short8*)&Wt[row * 128 + ((gc ^ (row & 7)) * 8)] = v;
        }
        #pragma unroll
        for (int it = 0; it < 2; ++it) {
            int m = it * 256 + tid;
            int row = m >> 4, gc = m & 15;
            const float* hp = h0 + (size_t)(t0 + row) * 1024 + ks * 128 + gc * 8;
            fv4 v0 = *(const fv4*)hp;
            fv4 v1 = *(const fv4*)(hp + 4);
            short8 ov;
            ov[0] = (short)f2bf(v0.x); ov[1] = (short)f2bf(v0.y);
            ov[2] = (short)f2bf(v0.z); ov[3] = (short)f2bf(v0.w);
            ov[4] = (short)f2bf(v1.x); ov[5] = (short)f2bf(v1.y);
            ov[6] = (short)f2bf(v1.z); ov[7] = (short)f2bf(v1.w);
            *(short8*)&Ht[row * 128 + ((gc ^ (row & 7)) * 8)] = ov;
        }
        __syncthreads();
        #pragma unroll
        for (int s = 0; s < 4; ++s) {
            int gk = s * 4 + g;
            int brow = wt * 16 + c;
            short8 b = *(const short8*)&Ht[brow * 128 + ((gk ^ (brow & 7)) * 8)];
            #pragma unroll
            for (int jf = 0; jf < 4; ++jf) {
                int j = wd * 64 + jf * 16 + c;
                short8 a = *(const short8*)&Wt[j * 128 + ((gk ^ (j & 7)) * 8)];
                acc[jf] = __builtin_amdgcn_mfma_f32_16x16x32_bf16(a, b, acc[jf], 0, 0, 0);
            }
        }
        __syncthreads();
    }
    const int tile = blockIdx.x * 2 + wt;
    const int erow = wt * 16 + c;
    #pragma unroll
    for (int f = 0; f < 4; ++f) {
        int d0 = wd * 64 + f * 16 + 4 * g;
        fv4 bi = *(const fv4*)(we0_bias + d0);
        float v0 = acc[f][0] + bi.x, v1 = acc[f][1] + bi.y;
        float v2 = acc[f][2] + bi.z, v3 = acc[f][3] + bi.w;
        // fp8 pack -> encF8
        int pk = __builtin_amdgcn_cvt_pk_fp8_f32(v0, v1, 0, false);
        pk = __builtin_amdgcn_cvt_pk_fp8_f32(v2, v3, pk, true);
        int s = wd * 2 + (f >> 1);
        int chunk = (f & 1) * 2 + (g >> 1);
        int e = (g & 1) * 4;
        *(unsigned*)(encF8 + (size_t)tile * 2048 + (chunk * 16 + c) * 32 + s * 8 + e) = (unsigned)pk;
        // bf16 -> LDS Et for fused logits
        us4 o;
        o.x = f2bf(v0); o.y = f2bf(v1); o.z = f2bf(v2); o.w = f2bf(v3);
        int cg = d0 >> 3, off = d0 & 7;
        *(us4*)&Et[erow * 128 + ((cg ^ (erow & 7)) * 8) + off] = o;
    }
    __syncthreads();

    short8 al[4][4];
    #pragma unroll
    for (int jf = 0; jf < 4; ++jf)
        #pragma unroll
        for (int s = 0; s < 4; ++s)
            al[jf][s] = *(const short8*)(wsb + (wd * 64 + jf * 16 + c) * 128 + s * 32 + g * 8);
    short8 bl[4];
    #pragma unroll
    for (int s = 0; s < 4; ++s) {
        int cg2 = s * 4 + g;
        bl[s] = *(const short8*)&Et[erow * 128 + ((cg2 ^ (erow & 7)) * 8)];
    }
    f32x4 acc2[4] = {};
    #pragma unroll
    for (int s = 0; s < 4; ++s)
        #pragma unroll
        for (int jf = 0; jf < 4; ++jf)
            acc2[jf] = __builtin_amdgcn_mfma_f32_16x16x32_bf16(al[jf][s], bl[s], acc2[jf], 0, 0, 0);
    const int tokc = t0 + wt * 16 + c;
    #pragma unroll
    for (int jf = 0; jf < 4; ++jf) {
        int m0 = wd * 64 + jf * 16 + 4 * g;
        fv4 bs = *(const fv4*)(ws_bias + m0);
        logT[(size_t)(m0 + 0) * N_TOK + tokc] = acc2[jf][0] + bs.x;
        logT[(size_t)(m0 + 1) * N_TOK + tokc] = acc2[jf][1] + bs.y;
        logT[(size_t)(m0 + 2) * N_TOK + tokc] = acc2[jf][2] + bs.z;
        logT[(size_t)(m0 + 3) * N_TOK + tokc] = acc2[jf][3] + bs.w;
    }
}

// ---------------- gate = softmax over axis 0, per column m (bf16, tiled) ----------------
__global__ __launch_bounds__(1024) void k_softmax0(const float* __restrict__ logT,
                                                   unsigned short* __restrict__ gateT) {
    __shared__ float red[32];
    const int m = blockIdx.x;
    const int tid = threadIdx.x;
    const int lane = tid & 63, wv = tid >> 6;   // 16 waves
    const float* row = logT + (size_t)m * N_TOK;

    fv4 v[4];
    float vmax = -3.0e38f;
    #pragma unroll
    for (int it = 0; it < 4; ++it) {
        v[it] = *(const fv4*)(row + it * 4096 + tid * 4);
        vmax = fmaxf(vmax, fmaxf(fmaxf(v[it].x, v[it].y), fmaxf(v[it].z, v[it].w)));
    }
    #pragma unroll
    for (int o = 32; o > 0; o >>= 1) vmax = fmaxf(vmax, __shfl_xor(vmax, o));
    if (lane == 0) red[wv] = vmax;
    __syncthreads();
    float bmax = -3.0e38f;
    #pragma unroll
    for (int k = 0; k < 16; ++k) bmax = fmaxf(bmax, red[k]);

    float s = 0.f;
    #pragma unroll
    for (int it = 0; it < 4; ++it) {
        v[it].x = __expf(v[it].x - bmax); v[it].y = __expf(v[it].y - bmax);
        v[it].z = __expf(v[it].z - bmax); v[it].w = __expf(v[it].w - bmax);
        s += v[it].x + v[it].y + v[it].z + v[it].w;
    }
    #pragma unroll
    for (int o = 32; o > 0; o >>= 1) s += __shfl_xor(s, o);
    if (lane == 0) red[16 + wv] = s;
    __syncthreads();
    float bs = 0.f;
    #pragma unroll
    for (int k = 0; k < 16; ++k) bs += red[16 + k];
    const float inv = 1.f / bs;

    const int q  = m >> 5;
    const int w8 = ((m >> 4) & 1) * 4 + (m & 3);
    const int gl = ((m & 15) >> 2) * 16;
    #pragma unroll
    for (int it = 0; it < 4; ++it) {
        int t = it * 4096 + tid * 4;
        float pv[4] = { v[it].x * inv, v[it].y * inv, v[it].z * inv, v[it].w * inv };
        #pragma unroll
        for (int k = 0; k < 4; ++k) {
            int tok = t + k;
            gateT[(size_t)(tok >> 4) * 2048 + q * 512 + (gl + (tok & 15)) * 8 + w8] = f2bf(pv[k]);
        }
    }
}

// ---------------- k_mix: fp8 panel, 3 waves/SIMD ----------------
// grid 768: i = bid&127 (module), part = bid>>7 in [0,6). Part p covers
// tile-groups [p*42+min(p,4), +42+(p<4)). 4 waves/block, wave w takes
// tile = group*4 + w. Panel 64 VGPR fp8 pinned; G issued before MFMA block
// (620cy shadow); enc prefetched after MFMA block.
__global__ __launch_bounds__(256)
__attribute__((amdgpu_waves_per_eu(3, 3)))
void k_mix(const unsigned char* __restrict__ wmf8,
           const unsigned char* __restrict__ encF8,
           const unsigned short* __restrict__ gateT,
           const float* __restrict__ wm_bias,
           unsigned short* __restrict__ mixT) {
    const int bid = blockIdx.x;
    const int i = bid & 127, part = bid >> 7;
    const int tid = threadIdx.x;
    const int lane = tid & 63, w = tid >> 6;
    const int c = lane & 15, g = lane >> 4;

    const unsigned char* wmi = wmf8 + (size_t)i * 16384;
    uint2 a[8][4];
    #pragma unroll
    for (int jf = 0; jf < 8; ++jf)
        #pragma unroll
        for (int s = 0; s < 4; ++s) {
            a[jf][s] = *(const uint2*)(wmi + (jf * 16 + c) * 128 + s * 32 + g * 8);
            asm volatile("" : "+v"(a[jf][s]));
        }
    f32x4 bias4[8];
    #pragma unroll
    for (int f = 0; f < 8; ++f) {
        bias4[f] = *(const f32x4*)(wm_bias + i * 128 + f * 16 + 4 * g);
        asm volatile("" : "+v"(bias4[f]));
    }

    const int start = part * 42 + (part < 4 ? part : 4);
    const int cnt = 42 + (part < 4 ? 1 : 0);
    const int si = i >> 5, ch = (i & 31) >> 3, ei = i & 7;

    const unsigned char* encB = encF8 + (size_t)(start * 4 + w) * 2048 + lane * 32;
    const unsigned* gateB = (const unsigned*)(gateT + (size_t)(start * 4 + w) * 2048) + lane * 4;
    unsigned short* mixB = mixT + (size_t)(start * 4 + w) * 2048 + si * 512 + (ch * 16 + lane) * 8 + ei;

    // prologue: enc frag for t=0
    uint4 q0 = *(const uint4*)(encB);
    uint4 q1 = *(const uint4*)(encB + 16);

    #pragma unroll 1
    for (int t = 0; t < cnt; ++t) {
        // gate loads for CURRENT tile: latency hides under the MFMA block
        const unsigned* gp = gateB + (size_t)t * 4096;
        uint4 G0 = *(const uint4*)(gp);
        uint4 G1 = *(const uint4*)(gp + 256);
        uint4 G2 = *(const uint4*)(gp + 512);
        uint4 G3 = *(const uint4*)(gp + 768);

        long b0 = __builtin_bit_cast(long, (uint2){q0.x, q0.y});
        long b1 = __builtin_bit_cast(long, (uint2){q0.z, q0.w});
        long b2 = __builtin_bit_cast(long, (uint2){q1.x, q1.y});
        long b3 = __builtin_bit_cast(long, (uint2){q1.z, q1.w});

        __builtin_amdgcn_s_setprio(1);
        f32x4 acc[8];
        #pragma unroll
        for (int jf = 0; jf < 8; ++jf)
            acc[jf] = __builtin_amdgcn_mfma_f32_16x16x32_fp8_fp8(
                __builtin_bit_cast(long, a[jf][0]), b0, bias4[jf], 0, 0, 0);
        #pragma unroll
        for (int jf = 0; jf < 8; ++jf)
            acc[jf] = __builtin_amdgcn_mfma_f32_16x16x32_fp8_fp8(
                __builtin_bit_cast(long, a[jf][1]), b1, acc[jf], 0, 0, 0);
        #pragma unroll
        for (int jf = 0; jf < 8; ++jf)
            acc[jf] = __builtin_amdgcn_mfma_f32_16x16x32_fp8_fp8(
                __builtin_bit_cast(long, a[jf][2]), b2, acc[jf], 0, 0, 0);
        #pragma unroll
        for (int jf = 0; jf < 8; ++jf)
            acc[jf] = __builtin_amdgcn_mfma_f32_16x16x32_fp8_fp8(
                __builtin_bit_cast(long, a[jf][3]), b3, acc[jf], 0, 0, 0);
        __builtin_amdgcn_s_setprio(0);

        // prefetch next tile's enc frag (consumed next iteration)
        {
            const int tn = (t + 1 < cnt) ? t + 1 : t;
            const unsigned char* ebn = encB + (size_t)tn * 8192;
            q0 = *(const uint4*)(ebn);
            q1 = *(const uint4*)(ebn + 16);
        }

        float p0 = 0.f, p1 = 0.f, p2 = 0.f, p3 = 0.f;
        #define EPI(F, GA, GB) {                                        \
            p0 += fmaxf(acc[F][0], 0.f) * bf2f_lo(GA);                  \
            p1 += fmaxf(acc[F][1], 0.f) * bf2f_hi(GA);                  \
            p2 += fmaxf(acc[F][2], 0.f) * bf2f_lo(GB);                  \
            p3 += fmaxf(acc[F][3], 0.f) * bf2f_hi(GB);                  \
        }
        EPI(0, G0.x, G0.y) EPI(1, G0.z, G0.w)
        EPI(2, G1.x, G1.y) EPI(3, G1.z, G1.w)
        EPI(4, G2.x, G2.y) EPI(5, G2.z, G2.w)
        EPI(6, G3.x, G3.y) EPI(7, G3.z, G3.w)
        #undef EPI
        float p = (p0 + p1) + (p2 + p3);
        p += __shfl_xor(p, 16);
        p += __shfl_xor(p, 32);
        if (lane < 16) *(mixB + (size_t)t * 8192) = f2bf(p);
    }
}

// ---------------- out = relu(mixed @ we1^T + b1 + h0) ----------------
__global__ __launch_bounds__(256)
__attribute__((amdgpu_waves_per_eu(2, 2)))
void k_dec(const unsigned short* __restrict__ we1b,
           const unsigned short* __restrict__ mixT,
           const float* __restrict__ we1_bias,
           const float* __restrict__ h0,
           float* __restrict__ out) {
    const int bid = blockIdx.x;
    const int eb = bid & 7, tg = bid >> 3;
    const int e0 = eb * 128;
    const int tid = threadIdx.x;
    const int lane = tid & 63, w = tid >> 6;
    const int c = lane & 15, g = lane >> 4;

    short8 a[8][4];
    #pragma unroll
    for (int jf = 0; jf < 8; ++jf)
        #pragma unroll
        for (int s = 0; s < 4; ++s) {
            a[jf][s] = *(const short8*)(we1b + (size_t)(e0 + jf * 16 + c) * 128 + s * 32 + g * 8);
            asm volatile("" : "+v"(a[jf][s]));
        }
    fv4 bi[8];
    #pragma unroll
    for (int f = 0; f < 8; ++f)
        bi[f] = *(const fv4*)(we1_bias + e0 + f * 16 + 4 * g);

    #pragma unroll 1
    for (int t = 0; t < 4; ++t) {
        const int tokr = tg * 256 + t * 64 + w * 16 + c;
        const int tile = tg * 16 + t * 4 + w;
        fv4 h[8];
        #pragma unroll
        for (int f = 0; f < 8; ++f)
            h[f] = *(const fv4*)(h0 + (size_t)tokr * 1024 + e0 + f * 16 + 4 * g);
        const unsigned short* mp = mixT + (size_t)tile * 2048 + lane * 8;
        short8 b[4];
        #pragma unroll
        for (int s = 0; s < 4; ++s)
            b[s] = *(const short8*)(mp + s * 512);

        f32x4 acc[8] = {};
        #pragma unroll
        for (int s = 0; s < 4; ++s)
            #pragma unroll
            for (int jf = 0; jf < 8; ++jf)
                acc[jf] = __builtin_amdgcn_mfma_f32_16x16x32_bf16(a[jf][s], b[s], acc[jf], 0, 0, 0);

        #pragma unroll
        for (int f = 0; f < 8; ++f) {
            fv4 o;
            o.x = fmaxf(acc[f][0] + bi[f].x + h[f].x, 0.f);
            o.y = fmaxf(acc[f][1] + bi[f].y + h[f].y, 0.f);
            o.z = fmaxf(acc[f][2] + bi[f].z + h[f].z, 0.f);
            o.w = fmaxf(acc[f][3] + bi[f].w + h[f].w, 0.f);
            *(fv4*)(out + (size_t)tokr * 1024 + e0 + f * 16 + 4 * g) = o;
        }
    }
}

extern "C" void kernel_launch(void* const* d_in, const int* in_sizes, int n_in,
                              void* d_out, int out_size, void* d_ws, size_t ws_size,
                              hipStream_t stream) {
    const float* h0    = (const float*)d_in[0];
    const float* we0_w = (const float*)d_in[1];
    const float* we0_b = (const float*)d_in[2];
    const float* ws_w  = (const float*)d_in[3];
    const float* ws_b  = (const float*)d_in[4];
    const float* wm_w  = (const float*)d_in[5];
    const float* wm_b  = (const float*)d_in[6];
    const float* we1_w = (const float*)d_in[7];
    const float* we1_b = (const float*)d_in[8];
    float* out = (float*)d_out;

    unsigned*       wmf8  = (unsigned*)d_ws;             // 2 MB (128*128*128 fp8)
    unsigned short* we0b  = (unsigned short*)(wmf8 + 524288);  // 128*1024 bf16
    unsigned short* we1b  = we0b + 131072;               // 1024*128 bf16
    unsigned short* wsb   = we1b + 131072;               // 128*128 bf16
    unsigned char*  encF8 = (unsigned char*)(wsb + 16384);     // 2 MB fp8 (tiled)
    float*          logT  = (float*)(encF8 + 2097152);   // [128][16384] f32
    unsigned short* gateT = (unsigned short*)(logT + 2097152); // 4 MB bf16 (tiled)
    unsigned short* mixT  = gateT + 2097152;             // 4 MB bf16 (tiled)

    k_convert_all<<<640, 256, 0, stream>>>(wm_w, we0_w, we1_w, ws_w, wmf8, we0b);
    k_enc<<<512, 256, 0, stream>>>(h0, we0b, wsb, we0_b, ws_b, encF8, logT);
    k_softmax0<<<128, 1024, 0, stream>>>(logT, gateT);
    k_mix<<<768, 256, 0, stream>>>((const unsigned char*)wmf8, encF8, gateT, wm_b, mixT);
    k_dec<<<512, 256, 0, stream>>>(we1b, mixT, we1_b, h0, out);
}